// Round 4
// baseline (178.163 us; speedup 1.0000x reference)
//
#include <hip/hip_runtime.h>
#include <hip/hip_cooperative_groups.h>
#include <math.h>

namespace cg = cooperative_groups;

// Fused quantization, one cooperative kernel (GRID=1024 -- the grid size that
// is known to pass cooperative-launch validation on this chip):
// phase 1: 4x-batched grid-stride float4 min/max -> per-block partials
// grid.sync()
// phase 2: every block reduces the partials (L2-hot)
// phase 3: 4x-batched grid-stride quantize; x re-read is L3-resident
//
// Latency hiding comes from MLP (4 independent float4 loads in flight per
// wave) rather than TLP. kernel_launch checks the cooperative-launch return
// code and falls back to a 3-kernel path if it is rejected (deterministic:
// the same branch is taken on every call).

#define BLOCK 256
#define COOP_GRID 1024
#define FB_GRID 2048

__device__ __forceinline__ void block_minmax_reduce(float vmin, float vmax,
                                                    float* smin, float* smax,
                                                    float* out_min, float* out_max) {
    #pragma unroll
    for (int off = 32; off > 0; off >>= 1) {
        vmin = fminf(vmin, __shfl_down(vmin, off, 64));
        vmax = fmaxf(vmax, __shfl_down(vmax, off, 64));
    }
    const int lane = threadIdx.x & 63;
    const int wave = threadIdx.x >> 6;
    if (lane == 0) { smin[wave] = vmin; smax[wave] = vmax; }
    __syncthreads();
    if (threadIdx.x == 0) {
        float bmin = smin[0], bmax = smax[0];
        #pragma unroll
        for (int w = 1; w < BLOCK / 64; ++w) {
            bmin = fminf(bmin, smin[w]);
            bmax = fmaxf(bmax, smax[w]);
        }
        *out_min = bmin;
        *out_max = bmax;
    }
}

__device__ __forceinline__ void local_minmax4(const float* __restrict__ x,
                                              long long n, long long tid,
                                              long long stride,
                                              float* vmin_out, float* vmax_out) {
    const long long n4 = n >> 2;
    const float4* __restrict__ x4 = (const float4*)x;
    float mn0 = INFINITY, mn1 = INFINITY, mn2 = INFINITY, mn3 = INFINITY;
    float mx0 = -INFINITY, mx1 = -INFINITY, mx2 = -INFINITY, mx3 = -INFINITY;
    long long i = tid;
    for (; i + 3 * stride < n4; i += 4 * stride) {
        float4 a = x4[i];
        float4 b = x4[i + stride];
        float4 c = x4[i + 2 * stride];
        float4 d = x4[i + 3 * stride];
        mn0 = fminf(mn0, fminf(fminf(a.x, a.y), fminf(a.z, a.w)));
        mx0 = fmaxf(mx0, fmaxf(fmaxf(a.x, a.y), fmaxf(a.z, a.w)));
        mn1 = fminf(mn1, fminf(fminf(b.x, b.y), fminf(b.z, b.w)));
        mx1 = fmaxf(mx1, fmaxf(fmaxf(b.x, b.y), fmaxf(b.z, b.w)));
        mn2 = fminf(mn2, fminf(fminf(c.x, c.y), fminf(c.z, c.w)));
        mx2 = fmaxf(mx2, fmaxf(fmaxf(c.x, c.y), fmaxf(c.z, c.w)));
        mn3 = fminf(mn3, fminf(fminf(d.x, d.y), fminf(d.z, d.w)));
        mx3 = fmaxf(mx3, fmaxf(fmaxf(d.x, d.y), fmaxf(d.z, d.w)));
    }
    for (; i < n4; i += stride) {
        float4 a = x4[i];
        mn0 = fminf(mn0, fminf(fminf(a.x, a.y), fminf(a.z, a.w)));
        mx0 = fmaxf(mx0, fmaxf(fmaxf(a.x, a.y), fmaxf(a.z, a.w)));
    }
    for (long long j = (n4 << 2) + tid; j < n; j += stride) {
        float v = x[j];
        mn0 = fminf(mn0, v);
        mx0 = fmaxf(mx0, v);
    }
    *vmin_out = fminf(fminf(mn0, mn1), fminf(mn2, mn3));
    *vmax_out = fmaxf(fmaxf(mx0, mx1), fmaxf(mx2, mx3));
}

#define QUANT1(v) (xmin + (fminf(fmaxf(floorf(((v) - xmin) * inv_step), 0.0f), 255.0f) + 0.5f) * step)
#define QUANT4(r, v) do { \
    (r).x = QUANT1((v).x); (r).y = QUANT1((v).y); \
    (r).z = QUANT1((v).z); (r).w = QUANT1((v).w); } while (0)

__device__ __forceinline__ void quant_body4(const float* __restrict__ x,
                                            float* __restrict__ out, long long n,
                                            long long tid, long long stride,
                                            float xmin, float xmax) {
    const float step = (xmax - xmin) * (1.0f / 256.0f);
    const float inv_step = 1.0f / step;
    const long long n4 = n >> 2;
    const float4* __restrict__ x4 = (const float4*)x;
    float4* __restrict__ o4 = (float4*)out;
    long long i = tid;
    for (; i + 3 * stride < n4; i += 4 * stride) {
        float4 a = x4[i];
        float4 b = x4[i + stride];
        float4 c = x4[i + 2 * stride];
        float4 d = x4[i + 3 * stride];
        float4 ra, rb, rc, rd;
        QUANT4(ra, a);
        QUANT4(rb, b);
        QUANT4(rc, c);
        QUANT4(rd, d);
        o4[i] = ra;
        o4[i + stride] = rb;
        o4[i + 2 * stride] = rc;
        o4[i + 3 * stride] = rd;
    }
    for (; i < n4; i += stride) {
        float4 a = x4[i];
        float4 ra;
        QUANT4(ra, a);
        o4[i] = ra;
    }
    for (long long j = (n4 << 2) + tid; j < n; j += stride) {
        out[j] = QUANT1(x[j]);
    }
}

// ---------------- fused cooperative kernel ----------------

__global__ __launch_bounds__(BLOCK, 4) void fused_quant_kernel(
    const float* __restrict__ x, float* __restrict__ out, long long n,
    float* __restrict__ partial) {
    cg::grid_group grid = cg::this_grid();

    const long long tid = (long long)blockIdx.x * blockDim.x + threadIdx.x;
    const long long stride = (long long)gridDim.x * blockDim.x;
    const int nblocks = gridDim.x;

    __shared__ float smin[BLOCK / 64], smax[BLOCK / 64];
    __shared__ float s_xmin, s_xmax;

    // phase 1
    float vmin, vmax;
    local_minmax4(x, n, tid, stride, &vmin, &vmax);
    block_minmax_reduce(vmin, vmax, smin, smax,
                        &partial[blockIdx.x], &partial[nblocks + blockIdx.x]);

    grid.sync();

    // phase 2: every block reduces all partials (L2-hot)
    float pmin = INFINITY, pmax = -INFINITY;
    for (int k = threadIdx.x; k < nblocks; k += BLOCK) {
        pmin = fminf(pmin, partial[k]);
        pmax = fmaxf(pmax, partial[nblocks + k]);
    }
    block_minmax_reduce(pmin, pmax, smin, smax, &s_xmin, &s_xmax);
    __syncthreads();

    // phase 3
    quant_body4(x, out, n, tid, stride, s_xmin, s_xmax);
}

// ---------------- fallback 3-kernel path ----------------

__global__ __launch_bounds__(BLOCK) void minmax_kernel(
    const float* __restrict__ x, long long n, float* __restrict__ partial,
    int nblocks) {
    const long long tid = (long long)blockIdx.x * blockDim.x + threadIdx.x;
    const long long stride = (long long)gridDim.x * blockDim.x;
    __shared__ float smin[BLOCK / 64], smax[BLOCK / 64];
    float vmin, vmax;
    local_minmax4(x, n, tid, stride, &vmin, &vmax);
    block_minmax_reduce(vmin, vmax, smin, smax,
                        &partial[blockIdx.x], &partial[nblocks + blockIdx.x]);
}

__global__ __launch_bounds__(BLOCK) void final_reduce_kernel(
    const float* __restrict__ partial, int nblocks, float* __restrict__ result) {
    __shared__ float smin[BLOCK / 64], smax[BLOCK / 64];
    float vmin = INFINITY, vmax = -INFINITY;
    for (int i = threadIdx.x; i < nblocks; i += BLOCK) {
        vmin = fminf(vmin, partial[i]);
        vmax = fmaxf(vmax, partial[nblocks + i]);
    }
    block_minmax_reduce(vmin, vmax, smin, smax, &result[0], &result[1]);
}

__global__ __launch_bounds__(BLOCK) void quant_kernel(
    const float* __restrict__ x, float* __restrict__ out, long long n,
    const float* __restrict__ mm) {
    const long long tid = (long long)blockIdx.x * blockDim.x + threadIdx.x;
    const long long stride = (long long)gridDim.x * blockDim.x;
    quant_body4(x, out, n, tid, stride, mm[0], mm[1]);
}

extern "C" void kernel_launch(void* const* d_in, const int* in_sizes, int n_in,
                              void* d_out, int out_size, void* d_ws, size_t ws_size,
                              hipStream_t stream) {
    const float* x = (const float*)d_in[0];
    float* out = (float*)d_out;
    long long n = (long long)in_sizes[0];
    float* ws = (float*)d_ws;
    // ws layout: [0..FB_GRID) mins, [FB_GRID..2*FB_GRID) maxs, [2*FB_GRID..+2) result
    float* partial = ws;
    float* result = ws + 2 * FB_GRID;

    void* args[] = {(void*)&x, (void*)&out, (void*)&n, (void*)&partial};
    hipError_t err = hipLaunchCooperativeKernel((const void*)fused_quant_kernel,
                                                dim3(COOP_GRID), dim3(BLOCK),
                                                args, 0, stream);
    if (err != hipSuccess) {
        // Deterministic fallback: plain 3-kernel path.
        minmax_kernel<<<FB_GRID, BLOCK, 0, stream>>>(x, n, partial, FB_GRID);
        final_reduce_kernel<<<1, BLOCK, 0, stream>>>(partial, FB_GRID, result);
        quant_kernel<<<FB_GRID, BLOCK, 0, stream>>>(x, out, n, result);
    }
}

// Round 5
// 69.431 us; speedup vs baseline: 2.5660x; 2.5660x over previous
//
#include <hip/hip_runtime.h>
#include <math.h>

// Two-kernel quantization pipeline (cooperative fusion abandoned: measured
// 2.5x slower than plain launches on gfx950).
//   kernel A: grid-stride float4 min/max -> per-block partials
//   kernel B: every block redundantly reduces the partials (16 KB, L3-hot),
//             then quantizes with non-temporal stores (keeps x L3-resident).

#define BLOCK 256
#define GRID 2048

typedef __attribute__((ext_vector_type(4))) float f32x4;

__global__ __launch_bounds__(BLOCK) void minmax_kernel(
    const float* __restrict__ x, long long n, float* __restrict__ partial) {
    long long tid = (long long)blockIdx.x * blockDim.x + threadIdx.x;
    long long stride = (long long)gridDim.x * blockDim.x;
    float vmin = INFINITY, vmax = -INFINITY;
    long long n4 = n >> 2;
    const float4* __restrict__ x4 = (const float4*)x;
    for (long long i = tid; i < n4; i += stride) {
        float4 v = x4[i];
        vmin = fminf(vmin, fminf(fminf(v.x, v.y), fminf(v.z, v.w)));
        vmax = fmaxf(vmax, fmaxf(fmaxf(v.x, v.y), fmaxf(v.z, v.w)));
    }
    for (long long i = (n4 << 2) + tid; i < n; i += stride) {
        float v = x[i];
        vmin = fminf(vmin, v);
        vmax = fmaxf(vmax, v);
    }
    #pragma unroll
    for (int off = 32; off > 0; off >>= 1) {
        vmin = fminf(vmin, __shfl_down(vmin, off, 64));
        vmax = fmaxf(vmax, __shfl_down(vmax, off, 64));
    }
    __shared__ float smin[BLOCK / 64], smax[BLOCK / 64];
    int lane = threadIdx.x & 63;
    int wave = threadIdx.x >> 6;
    if (lane == 0) { smin[wave] = vmin; smax[wave] = vmax; }
    __syncthreads();
    if (threadIdx.x == 0) {
        float bmin = smin[0], bmax = smax[0];
        #pragma unroll
        for (int w = 1; w < BLOCK / 64; ++w) {
            bmin = fminf(bmin, smin[w]);
            bmax = fmaxf(bmax, smax[w]);
        }
        partial[blockIdx.x] = bmin;
        partial[GRID + blockIdx.x] = bmax;
    }
}

__global__ __launch_bounds__(BLOCK) void quant_kernel(
    const float* __restrict__ x, float* __restrict__ out, long long n,
    const float* __restrict__ partial) {
    // ---- prologue: every block reduces the 2048 partials (L3-hot) ----
    __shared__ float smin[BLOCK / 64], smax[BLOCK / 64];
    __shared__ float s_xmin, s_xmax;
    float pmin = INFINITY, pmax = -INFINITY;
    for (int k = threadIdx.x; k < GRID; k += BLOCK) {
        pmin = fminf(pmin, partial[k]);
        pmax = fmaxf(pmax, partial[GRID + k]);
    }
    #pragma unroll
    for (int off = 32; off > 0; off >>= 1) {
        pmin = fminf(pmin, __shfl_down(pmin, off, 64));
        pmax = fmaxf(pmax, __shfl_down(pmax, off, 64));
    }
    int lane = threadIdx.x & 63;
    int wave = threadIdx.x >> 6;
    if (lane == 0) { smin[wave] = pmin; smax[wave] = pmax; }
    __syncthreads();
    if (threadIdx.x == 0) {
        float bmin = smin[0], bmax = smax[0];
        #pragma unroll
        for (int w = 1; w < BLOCK / 64; ++w) {
            bmin = fminf(bmin, smin[w]);
            bmax = fmaxf(bmax, smax[w]);
        }
        s_xmin = bmin;
        s_xmax = bmax;
    }
    __syncthreads();

    // ---- quantize ----
    const float xmin = s_xmin;
    const float xmax = s_xmax;
    const float step = (xmax - xmin) * (1.0f / 256.0f);
    const float inv_step = 1.0f / step;

    long long tid = (long long)blockIdx.x * blockDim.x + threadIdx.x;
    long long stride = (long long)gridDim.x * blockDim.x;
    long long n4 = n >> 2;
    const float4* __restrict__ x4 = (const float4*)x;
    f32x4* __restrict__ o4 = (f32x4*)out;

    for (long long i = tid; i < n4; i += stride) {
        float4 v = x4[i];
        f32x4 r;
        float ix = fminf(fmaxf(floorf((v.x - xmin) * inv_step), 0.0f), 255.0f);
        float iy = fminf(fmaxf(floorf((v.y - xmin) * inv_step), 0.0f), 255.0f);
        float iz = fminf(fmaxf(floorf((v.z - xmin) * inv_step), 0.0f), 255.0f);
        float iw = fminf(fmaxf(floorf((v.w - xmin) * inv_step), 0.0f), 255.0f);
        r.x = xmin + (ix + 0.5f) * step;
        r.y = xmin + (iy + 0.5f) * step;
        r.z = xmin + (iz + 0.5f) * step;
        r.w = xmin + (iw + 0.5f) * step;
        // Non-temporal: out is write-once; keep x resident in L3 instead.
        __builtin_nontemporal_store(r, &o4[i]);
    }
    for (long long i = (n4 << 2) + tid; i < n; i += stride) {
        float v = x[i];
        float idx = fminf(fmaxf(floorf((v - xmin) * inv_step), 0.0f), 255.0f);
        __builtin_nontemporal_store(xmin + (idx + 0.5f) * step, &out[i]);
    }
}

extern "C" void kernel_launch(void* const* d_in, const int* in_sizes, int n_in,
                              void* d_out, int out_size, void* d_ws, size_t ws_size,
                              hipStream_t stream) {
    const float* x = (const float*)d_in[0];
    float* out = (float*)d_out;
    long long n = (long long)in_sizes[0];
    float* partial = (float*)d_ws;  // [0..GRID) mins, [GRID..2*GRID) maxs

    minmax_kernel<<<GRID, BLOCK, 0, stream>>>(x, n, partial);
    quant_kernel<<<GRID, BLOCK, 0, stream>>>(x, out, n, partial);
}